// Round 5
// baseline (34.228 us; speedup 1.0000x reference)
//
#include <hip/hip_runtime.h>

// SNN autoencoder collapses to: m_e = x @ enc_w ; m_d = m_e @ dec_w
// (spike state is exactly {0,1}, so 0.9*s - 0.9*(s>0.9) == 0 every step;
//  membranes are recomputed from the constant input current each step).
// Output: d_out = [m_d (2048x1024) | m_e (2048x256)], fp32.
//
// 2 dispatches:
//   prep  : x->bf16, enc->bf16 transposed [N][K], dec->bf16 transposed [N][K]
//   fused : per 32-row strip: GEMM1 (K=1024 dbuf loop) -> m_e strip in LDS ->
//           GEMM2 (16 x 64-col chunks of decT, dbuf loop). No inter-block deps:
//           m_d rows depend only on m_e rows of the same strip.

typedef __attribute__((ext_vector_type(8))) short bf16x8;
typedef __attribute__((ext_vector_type(4))) float f32x4;
typedef __attribute__((ext_vector_type(8))) unsigned short ushort8;

__device__ __forceinline__ unsigned short f2bf(float f) {
    unsigned u = __builtin_bit_cast(unsigned, f);
    unsigned r = u + 0x7FFFu + ((u >> 16) & 1u);   // RNE
    return (unsigned short)(r >> 16);
}

__device__ __forceinline__ void gload_lds16(const unsigned short* src,
                                            unsigned short* dst) {
    __builtin_amdgcn_global_load_lds(
        (const __attribute__((address_space(1))) void*)src,
        (__attribute__((address_space(3))) void*)dst, 16, 0, 0);
}

// ---------------- fused GEMM1+GEMM2, one 32-row strip per block --------------
// 512 threads = 8 waves in a 2x4 grid (wr in {0,1}: 16-row half; wc in 0..3).
__global__ __launch_bounds__(512) void fused_gemm(
    const unsigned short* __restrict__ x_bf,   // [2048][1024] bf16
    const unsigned short* __restrict__ encT,   // [256][1024] bf16
    const unsigned short* __restrict__ decT,   // [1024][256] bf16
    float* __restrict__ m_e,                   // [2048][256] f32
    float* __restrict__ m_d)                   // [2048][1024] f32
{
    constexpr int K1 = 1024, N1 = 256, K2 = 256, N2 = 1024, BM = 32, BK = 64;
    // 16 KB me strip + 2 x 36 KB (phase A: A tile 4KB + B tile 32KB;
    // phase B reuses 32KB of each half for the decT chunk) = 88 KB.
    __shared__ __align__(16) unsigned short sm_me[BM * 256];
    __shared__ __align__(16) unsigned short sm_big[2][BM * BK + 256 * BK];

    const int t = threadIdx.x;
    const int lane = t & 63;
    const int l15 = lane & 15, l4 = lane >> 4;
    const int wid = t >> 6;
    const int wr = wid >> 2;          // 0..1
    const int wc = wid & 3;           // 0..3
    const int brow = blockIdx.x * BM;

    // ================= phase A: m_e strip = x[brow..+31] @ encT ==============
    f32x4 acc[4];
    #pragma unroll
    for (int j = 0; j < 4; ++j) acc[j] = {0.f, 0.f, 0.f, 0.f};

    auto stageA = [&](int kt, unsigned short* buf) {
        // A tile [32 rows][64 k]: 256 x 16B chunks (waves 0-3 only)
        if (t < 256) {
            const int row = t >> 3, cc = t & 7;
            const unsigned short* src =
                x_bf + (size_t)(brow + row) * K1 + kt * BK + (cc ^ (row & 7)) * 8;
            gload_lds16(src, buf + (size_t)(t & ~63) * 8);
        }
        // B tile [256 rows][64 k]: 2048 chunks, 4 per thread
        unsigned short* bbuf = buf + BM * BK;
        #pragma unroll
        for (int c = 0; c < 4; ++c) {
            const int idx = c * 512 + t;
            const int row = idx >> 3, cc = idx & 7;
            const unsigned short* src =
                encT + (size_t)row * K1 + kt * BK + (cc ^ (row & 7)) * 8;
            gload_lds16(src, bbuf + (size_t)(idx & ~63) * 8);
        }
    };

    stageA(0, sm_big[0]);
    for (int kt = 0; kt < K1 / BK; ++kt) {
        __syncthreads();            // stage(kt) landed; buf[(kt)&1^1] free
        if (kt + 1 < K1 / BK) stageA(kt + 1, sm_big[(kt + 1) & 1]);
        const unsigned short* As = sm_big[kt & 1];
        const unsigned short* Bs = As + BM * BK;
        const int ra = wr * 16 + l15;
        #pragma unroll
        for (int s = 0; s < 2; ++s) {
            const int ca = (s * 4 + l4) ^ (ra & 7);
            const bf16x8 aF = *(const bf16x8*)&As[ra * BK + ca * 8];
            #pragma unroll
            for (int j = 0; j < 4; ++j) {
                const int rb = wc * 64 + j * 16 + l15;
                const int cb = (s * 4 + l4) ^ (rb & 7);
                const bf16x8 bF = *(const bf16x8*)&Bs[rb * BK + cb * 8];
                acc[j] = __builtin_amdgcn_mfma_f32_16x16x32_bf16(aF, bF, acc[j], 0, 0, 0);
            }
        }
    }

    // ---- epilogue A: m_e f32 to global, bf16 into sm_me (XOR-swizzled) ----
    #pragma unroll
    for (int j = 0; j < 4; ++j)
        #pragma unroll
        for (int reg = 0; reg < 4; ++reg) {
            const int r = wr * 16 + l4 * 4 + reg;       // 0..31
            const int ccol = wc * 64 + j * 16 + l15;    // 0..255
            const float v = acc[j][reg];
            m_e[(size_t)(brow + r) * N1 + ccol] = v;
            const int cc = (ccol >> 3) ^ (r & 7);       // 3-bit XOR on chunk idx
            sm_me[r * 256 + cc * 8 + (ccol & 7)] = f2bf(v);
        }

    __syncthreads();   // phase-A reads & sm_me writes complete before reuse

    // ================= phase B: m_d strip = me_strip @ decT ==================
    // hoist the 8 A-fragments (reused by all 16 chunks)
    bf16x8 aF2[8];
    {
        const int ra = wr * 16 + l15;
        #pragma unroll
        for (int ks = 0; ks < 8; ++ks) {
            const int ca = (ks * 4 + l4) ^ (ra & 7);
            aF2[ks] = *(const bf16x8*)&sm_me[ra * 256 + ca * 8];
        }
    }

    auto stageD = [&](int nc, unsigned short* buf) {
        // decT chunk [64 rows][256 k]: 2048 chunks, 4 per thread
        #pragma unroll
        for (int c = 0; c < 4; ++c) {
            const int idx = c * 512 + t;
            const int row = idx >> 5, cc = idx & 31;
            const unsigned short* src =
                decT + (size_t)(nc * 64 + row) * K2 + (cc ^ (row & 7)) * 8;
            gload_lds16(src, buf + (size_t)(idx & ~63) * 8);
        }
    };

    stageD(0, sm_big[0]);
    for (int nc = 0; nc < 16; ++nc) {
        __syncthreads();
        if (nc + 1 < 16) stageD(nc + 1, sm_big[(nc + 1) & 1]);
        const unsigned short* Ds = sm_big[nc & 1];
        f32x4 acc2 = {0.f, 0.f, 0.f, 0.f};
        const int rb = wc * 16 + l15;                   // 0..63 (chunk-local col)
        #pragma unroll
        for (int ks = 0; ks < 8; ++ks) {
            const int cb = (ks * 4 + l4) ^ (rb & 7);
            const bf16x8 bF = *(const bf16x8*)&Ds[rb * K2 + cb * 8];
            acc2 = __builtin_amdgcn_mfma_f32_16x16x32_bf16(aF2[ks], bF, acc2, 0, 0, 0);
        }
        #pragma unroll
        for (int reg = 0; reg < 4; ++reg) {
            const int row = brow + wr * 16 + l4 * 4 + reg;
            const int col = nc * 64 + wc * 16 + l15;
            m_d[(size_t)row * N2 + col] = acc2[reg];
        }
    }
}

// ---------------- fused prep: x->bf16 | enc transpose | dec transpose --------
__global__ __launch_bounds__(256) void prep(
    const float* __restrict__ x, const float* __restrict__ enc,
    const float* __restrict__ dec, unsigned short* __restrict__ x_bf,
    unsigned short* __restrict__ encT, unsigned short* __restrict__ decT)
{
    __shared__ unsigned short tile[32][33];
    const int bid = blockIdx.x;
    const int t = threadIdx.x;

    if (bid < 1024) {               // ---- x cvt: 2M elems, 8/thread ----
        const int i = bid * 256 + t;
        float4 a = ((const float4*)x)[2 * i];
        float4 b = ((const float4*)x)[2 * i + 1];
        ushort8 v;
        v[0] = f2bf(a.x); v[1] = f2bf(a.y); v[2] = f2bf(a.z); v[3] = f2bf(a.w);
        v[4] = f2bf(b.x); v[5] = f2bf(b.y); v[6] = f2bf(b.z); v[7] = f2bf(b.w);
        ((ushort8*)x_bf)[i] = v;
        return;
    }
    const float* in; unsigned short* out; int R, C, bx, by;
    if (bid < 1280) {               // enc [1024][256] -> encT [256][1024]
        const int bb = bid - 1024;
        in = enc; out = encT; R = 1024; C = 256; bx = bb % 8; by = bb / 8;
    } else {                        // dec [256][1024] -> decT [1024][256]
        const int bb = bid - 1280;
        in = dec; out = decT; R = 256; C = 1024; bx = bb % 32; by = bb / 32;
    }
    const int r0 = by * 32, c0 = bx * 32;
    const int tx = t % 32, ty = t / 32;       // 32 x 8
    #pragma unroll
    for (int k = 0; k < 4; ++k) {
        const int lr = ty + k * 8;
        tile[lr][tx] = f2bf(in[(size_t)(r0 + lr) * C + c0 + tx]);
    }
    __syncthreads();
    #pragma unroll
    for (int k = 0; k < 4; ++k) {
        const int lc = ty + k * 8;
        out[(size_t)(c0 + lc) * R + r0 + tx] = tile[tx][lc];
    }
}

// ---------------- fp32 fallback ----------------
#define BKF 32
#define PADF 4
template <int BM, int BN, int TM, int TN>
__global__ __launch_bounds__(256) void gemm_f32(
    const float* __restrict__ A, const float* __restrict__ B,
    float* __restrict__ C, int M, int N, int K)
{
    __shared__ float As[BKF][BM + PADF];
    __shared__ float Bs[BKF][BN + PADF];
    const int t = threadIdx.x;
    const int brow = blockIdx.y * BM, bcol = blockIdx.x * BN;
    constexpr int NTX = BN / TN;
    const int tx = t % NTX, ty = t / NTX;
    float acc[TM][TN];
    #pragma unroll
    for (int i = 0; i < TM; ++i)
        #pragma unroll
        for (int j = 0; j < TN; ++j) acc[i][j] = 0.f;
    for (int k0 = 0; k0 < K; k0 += BKF) {
        #pragma unroll
        for (int v = t; v < BM * BKF / 4; v += 256) {
            const int row = v / (BKF / 4), kv = v % (BKF / 4);
            const float4 val = *(const float4*)&A[(size_t)(brow + row) * K + k0 + kv * 4];
            As[kv * 4 + 0][row] = val.x; As[kv * 4 + 1][row] = val.y;
            As[kv * 4 + 2][row] = val.z; As[kv * 4 + 3][row] = val.w;
        }
        #pragma unroll
        for (int v = t; v < BKF * BN / 4; v += 256) {
            const int kk = v / (BN / 4), cv = v % (BN / 4);
            *(float4*)&Bs[kk][cv * 4] = *(const float4*)&B[(size_t)(k0 + kk) * N + bcol + cv * 4];
        }
        __syncthreads();
        #pragma unroll
        for (int k = 0; k < BKF; ++k) {
            float a[TM], b[TN];
            #pragma unroll
            for (int i = 0; i < TM; ++i) a[i] = As[k][ty * TM + i];
            #pragma unroll
            for (int j = 0; j < TN; ++j) b[j] = Bs[k][tx * TN + j];
            #pragma unroll
            for (int i = 0; i < TM; ++i)
                #pragma unroll
                for (int j = 0; j < TN; ++j) acc[i][j] = fmaf(a[i], b[j], acc[i][j]);
        }
        __syncthreads();
    }
    #pragma unroll
    for (int i = 0; i < TM; ++i)
        #pragma unroll
        for (int j = 0; j < TN; ++j)
            C[(size_t)(brow + ty * TM + i) * N + bcol + tx * TN + j] = acc[i][j];
}

extern "C" void kernel_launch(void* const* d_in, const int* in_sizes, int n_in,
                              void* d_out, int out_size, void* d_ws, size_t ws_size,
                              hipStream_t stream) {
    const float* x     = (const float*)d_in[0];  // [2048, 1024]
    const float* enc_w = (const float*)d_in[1];  // [1024, 256]
    const float* dec_w = (const float*)d_in[2];  // [256, 1024]

    const int B = 2048, D = 1024, H = 256;
    float* m_d = (float*)d_out;
    float* m_e = (float*)d_out + (size_t)B * D;

    const size_t need = (size_t)B * D * 2 + (size_t)D * H * 2 * 2;
    if (ws_size >= need) {
        unsigned short* x_bf = (unsigned short*)d_ws;             // [2048][1024]
        unsigned short* encT = x_bf + (size_t)B * D;              // [256][1024]
        unsigned short* decT = encT + (size_t)H * D;              // [1024][256]

        prep<<<dim3(1536), dim3(256), 0, stream>>>(x, enc_w, dec_w, x_bf, encT, decT);
        fused_gemm<<<dim3(B / 32), dim3(512), 0, stream>>>(x_bf, encT, decT, m_e, m_d);
    } else {
        gemm_f32<64, 32, 4, 2><<<dim3(H / 32, B / 64), dim3(256), 0, stream>>>(x, enc_w, m_e, B, H, D);
        gemm_f32<64, 64, 4, 4><<<dim3(D / 64, B / 64), dim3(256), 0, stream>>>(m_e, dec_w, m_d, B, D, H);
    }
}

// Round 6
// 29.182 us; speedup vs baseline: 1.1729x; 1.1729x over previous
//
#include <hip/hip_runtime.h>

// SNN autoencoder collapses to: m_e = x @ enc_w ; m_d = m_e @ dec_w
// (spike state is exactly {0,1}, so 0.9*s - 0.9*(s>0.9) == 0 every step;
//  membranes are recomputed from the constant input current each step).
// Output: d_out = [m_d (2048x1024) | m_e (2048x256)], fp32.
//
// 3 dispatches:
//   prep_t : enc->bf16 transposed [N][K], dec->bf16 transposed [N][K] (512 blocks)
//   gemm1  : m_e = x @ enc_w — 32x32 tiles, BK=128 (8 barrier iters),
//            A staged f32 straight from x (cvt at fragment read), dbuf
//   gemm2  : m_d = m_e @ dec_w (K=256 LDS-resident, 1 barrier, 1024 blocks)

typedef __attribute__((ext_vector_type(8))) short bf16x8;
typedef __attribute__((ext_vector_type(4))) float f32x4;
typedef __attribute__((ext_vector_type(8))) unsigned short ushort8;

__device__ __forceinline__ unsigned short f2bf(float f) {
    unsigned u = __builtin_bit_cast(unsigned, f);
    unsigned r = u + 0x7FFFu + ((u >> 16) & 1u);   // RNE
    return (unsigned short)(r >> 16);
}

__device__ __forceinline__ void gload_lds16(const void* src, void* dst) {
    __builtin_amdgcn_global_load_lds(
        (const __attribute__((address_space(1))) void*)src,
        (__attribute__((address_space(3))) void*)dst, 16, 0, 0);
}

// ---- stage ROWS x 64 bf16 tile (8 chunks/row, XOR-swizzled source, rule #21) ----
template <int ROWS>
__device__ __forceinline__ void stage_tile(const unsigned short* __restrict__ g,
                                           int ld, unsigned short* lds, int t) {
    #pragma unroll
    for (int c = 0; c < ROWS / 32; ++c) {
        const int idx = c * 256 + t;          // 16B-chunk index in tile
        const int row = idx >> 3;
        const int chunk = (idx & 7) ^ (row & 7);
        const unsigned short* src = g + (size_t)row * ld + chunk * 8;
        unsigned short* dst = lds + (size_t)(idx & ~63) * 8;  // wave-uniform base
        gload_lds16(src, dst);
    }
}

// ---------------- GEMM1: 32x32 tiles, BK=128, A = f32 x directly -------------
// LDS: As f32 [2][32*128] = 32 KB, Bs bf16 [2][32*128] = 16 KB. 8 K-iters.
__global__ __launch_bounds__(256) void gemm1_bk128(
    const float* __restrict__ x,            // [2048][1024] f32
    const unsigned short* __restrict__ Bt,  // [256][1024] bf16 (encT)
    float* __restrict__ C,                  // [2048][256] f32 (m_e)
    unsigned short* __restrict__ Cbf)       // [2048][256] bf16
{
    constexpr int N = 256, K = 1024, BK = 128, NT = K / BK;
    __shared__ __align__(16) float          As[2][32 * BK];
    __shared__ __align__(16) unsigned short Bs[2][32 * BK];

    const int t = threadIdx.x;
    const int lane = t & 63;
    const int l15 = lane & 15, l4 = lane >> 4;
    const int wid = t >> 6;
    const int wr = wid >> 1, wc = wid & 1;          // 2x2 waves, WM=WN=16
    const int brow = blockIdx.y * 32, bcol = blockIdx.x * 32;

    const float* Ab = x + (size_t)brow * K;
    const unsigned short* Bb = Bt + (size_t)bcol * K;

    auto stage = [&](int kt, int buf) {
        // A tile [32 rows][128 k] f32: 32 chunks/row, 1024 chunks, 4/thread
        #pragma unroll
        for (int c = 0; c < 4; ++c) {
            const int idx = c * 256 + t;
            const int row = idx >> 5;
            const int ch = (idx & 31) ^ (row & 31);
            gload_lds16(Ab + (size_t)row * K + kt * BK + ch * 4,
                        &As[buf][(idx & ~63) * 4]);
        }
        // B tile [32 rows][128 k] bf16: 16 chunks/row, 512 chunks, 2/thread
        #pragma unroll
        for (int c = 0; c < 2; ++c) {
            const int idx = c * 256 + t;
            const int row = idx >> 4;
            const int ch = (idx & 15) ^ (row & 15);
            gload_lds16(Bb + (size_t)row * K + kt * BK + ch * 8,
                        &Bs[buf][(idx & ~63) * 8]);
        }
    };

    f32x4 acc = {0.f, 0.f, 0.f, 0.f};
    stage(0, 0);
    for (int kt = 0; kt < NT; ++kt) {
        __syncthreads();            // stage(kt) landed; other buffer reads done
        if (kt + 1 < NT) stage(kt + 1, (kt + 1) & 1);
        const float* Asb = As[kt & 1];
        const unsigned short* Bsb = Bs[kt & 1];
        const int ra = wr * 16 + l15;
        const int rb = wc * 16 + l15;
        #pragma unroll
        for (int s = 0; s < 4; ++s) {           // 4 x 32-k MFMA steps
            const int c0 = (s * 8 + l4 * 2) ^ (ra & 31);
            const int c1 = (s * 8 + l4 * 2 + 1) ^ (ra & 31);
            const f32x4 a0 = *(const f32x4*)&Asb[ra * BK + c0 * 4];
            const f32x4 a1 = *(const f32x4*)&Asb[ra * BK + c1 * 4];
            bf16x8 aF;
            aF[0] = (short)f2bf(a0[0]); aF[1] = (short)f2bf(a0[1]);
            aF[2] = (short)f2bf(a0[2]); aF[3] = (short)f2bf(a0[3]);
            aF[4] = (short)f2bf(a1[0]); aF[5] = (short)f2bf(a1[1]);
            aF[6] = (short)f2bf(a1[2]); aF[7] = (short)f2bf(a1[3]);
            const int cb = (s * 4 + l4) ^ (rb & 15);
            const bf16x8 bF = *(const bf16x8*)&Bsb[rb * BK + cb * 8];
            acc = __builtin_amdgcn_mfma_f32_16x16x32_bf16(aF, bF, acc, 0, 0, 0);
        }
    }

    #pragma unroll
    for (int reg = 0; reg < 4; ++reg) {
        const int row = brow + wr * 16 + l4 * 4 + reg;
        const int col = bcol + wc * 16 + l15;
        const float v = acc[reg];
        C[(size_t)row * N + col] = v;
        Cbf[(size_t)row * N + col] = f2bf(v);
    }
}

// ---------------- GEMM2: K=256 LDS-resident, single barrier (r3-proven) ------
__global__ __launch_bounds__(256) void gemm2_kres(
    const unsigned short* __restrict__ A,   // [2048][256] bf16 (m_e)
    const unsigned short* __restrict__ B,   // [1024][256] bf16 (decT)
    float* __restrict__ C)                  // [2048][1024] f32 (m_d)
{
    constexpr int K = 256, N = 1024;
    __shared__ __align__(16) unsigned short As[4][32 * 64];  // 16 KB
    __shared__ __align__(16) unsigned short Bs[4][64 * 64];  // 32 KB

    const int t = threadIdx.x;
    const int lane = t & 63;
    const int l15 = lane & 15, l4 = lane >> 4;
    const int wid = t >> 6;
    const int wr = wid >> 1, wc = wid & 1;
    const int brow = blockIdx.y * 32, bcol = blockIdx.x * 64;

    #pragma unroll
    for (int kt = 0; kt < 4; ++kt) {
        stage_tile<32>(A + (size_t)brow * K + kt * 64, K, As[kt], t);
        stage_tile<64>(B + (size_t)bcol * K + kt * 64, K, Bs[kt], t);
    }
    __syncthreads();

    f32x4 acc[2] = {{0.f, 0.f, 0.f, 0.f}, {0.f, 0.f, 0.f, 0.f}};
    #pragma unroll
    for (int kt = 0; kt < 4; ++kt)
        #pragma unroll
        for (int s = 0; s < 2; ++s) {
            const int ra = wr * 16 + l15;
            const int cha = (s * 4 + l4) ^ (ra & 7);
            bf16x8 aF = *(const bf16x8*)&As[kt][ra * 64 + cha * 8];
            #pragma unroll
            for (int j = 0; j < 2; ++j) {
                const int rb = wc * 32 + j * 16 + l15;
                const int chb = (s * 4 + l4) ^ (rb & 7);
                bf16x8 bF = *(const bf16x8*)&Bs[kt][rb * 64 + chb * 8];
                acc[j] = __builtin_amdgcn_mfma_f32_16x16x32_bf16(aF, bF, acc[j], 0, 0, 0);
            }
        }

    #pragma unroll
    for (int j = 0; j < 2; ++j)
        #pragma unroll
        for (int reg = 0; reg < 4; ++reg) {
            const int row = brow + wr * 16 + l4 * 4 + reg;
            const int col = bcol + wc * 32 + j * 16 + l15;
            C[(size_t)row * N + col] = acc[j][reg];
        }
}

// ---------------- prep: enc transpose | dec transpose (512 blocks, r4-proven) -
__global__ __launch_bounds__(256) void prep_t(
    const float* __restrict__ enc, const float* __restrict__ dec,
    unsigned short* __restrict__ encT, unsigned short* __restrict__ decT)
{
    __shared__ unsigned short tile[32][33];
    const int bid = blockIdx.x;
    const int t = threadIdx.x;

    const float* in; unsigned short* out; int R, C, bx, by;
    if (bid < 256) {                // enc [1024][256] -> encT [256][1024]
        in = enc; out = encT; R = 1024; C = 256; bx = bid % 8; by = bid / 8;
    } else {                        // dec [256][1024] -> decT [1024][256]
        const int bb = bid - 256;
        in = dec; out = decT; R = 256; C = 1024; bx = bb % 32; by = bb / 32;
    }
    const int r0 = by * 32, c0 = bx * 32;
    const int tx = t % 32, ty = t / 32;       // 32 x 8
    #pragma unroll
    for (int k = 0; k < 4; ++k) {
        const int lr = ty + k * 8;
        tile[lr][tx] = f2bf(in[(size_t)(r0 + lr) * C + c0 + tx]);
    }
    __syncthreads();
    #pragma unroll
    for (int k = 0; k < 4; ++k) {
        const int lc = ty + k * 8;
        out[(size_t)(c0 + lc) * R + r0 + tx] = tile[tx][lc];
    }
}

// ---------------- fp32 fallback ----------------
#define BKF 32
#define PADF 4
template <int BM, int BN, int TM, int TN>
__global__ __launch_bounds__(256) void gemm_f32(
    const float* __restrict__ A, const float* __restrict__ B,
    float* __restrict__ C, int M, int N, int K)
{
    __shared__ float As[BKF][BM + PADF];
    __shared__ float Bs[BKF][BN + PADF];
    const int t = threadIdx.x;
    const int brow = blockIdx.y * BM, bcol = blockIdx.x * BN;
    constexpr int NTX = BN / TN;
    const int tx = t % NTX, ty = t / NTX;
    float acc[TM][TN];
    #pragma unroll
    for (int i = 0; i < TM; ++i)
        #pragma unroll
        for (int j = 0; j < TN; ++j) acc[i][j] = 0.f;
    for (int k0 = 0; k0 < K; k0 += BKF) {
        #pragma unroll
        for (int v = t; v < BM * BKF / 4; v += 256) {
            const int row = v / (BKF / 4), kv = v % (BKF / 4);
            const float4 val = *(const float4*)&A[(size_t)(brow + row) * K + k0 + kv * 4];
            As[kv * 4 + 0][row] = val.x; As[kv * 4 + 1][row] = val.y;
            As[kv * 4 + 2][row] = val.z; As[kv * 4 + 3][row] = val.w;
        }
        #pragma unroll
        for (int v = t; v < BKF * BN / 4; v += 256) {
            const int kk = v / (BN / 4), cv = v % (BN / 4);
            *(float4*)&Bs[kk][cv * 4] = *(const float4*)&B[(size_t)(k0 + kk) * N + bcol + cv * 4];
        }
        __syncthreads();
        #pragma unroll
        for (int k = 0; k < BKF; ++k) {
            float a[TM], b[TN];
            #pragma unroll
            for (int i = 0; i < TM; ++i) a[i] = As[k][ty * TM + i];
            #pragma unroll
            for (int j = 0; j < TN; ++j) b[j] = Bs[k][tx * TN + j];
            #pragma unroll
            for (int i = 0; i < TM; ++i)
                #pragma unroll
                for (int j = 0; j < TN; ++j) acc[i][j] = fmaf(a[i], b[j], acc[i][j]);
        }
        __syncthreads();
    }
    #pragma unroll
    for (int i = 0; i < TM; ++i)
        #pragma unroll
        for (int j = 0; j < TN; ++j)
            C[(size_t)(brow + ty * TM + i) * N + bcol + tx * TN + j] = acc[i][j];
}

extern "C" void kernel_launch(void* const* d_in, const int* in_sizes, int n_in,
                              void* d_out, int out_size, void* d_ws, size_t ws_size,
                              hipStream_t stream) {
    const float* x     = (const float*)d_in[0];  // [2048, 1024]
    const float* enc_w = (const float*)d_in[1];  // [1024, 256]
    const float* dec_w = (const float*)d_in[2];  // [256, 1024]

    const int B = 2048, D = 1024, H = 256;
    float* m_d = (float*)d_out;
    float* m_e = (float*)d_out + (size_t)B * D;

    const size_t need = (size_t)D * H * 2 * 2 + (size_t)B * H * 2;
    if (ws_size >= need) {
        unsigned short* encT  = (unsigned short*)d_ws;            // [256][1024]
        unsigned short* decT  = encT + (size_t)H * D;             // [1024][256]
        unsigned short* me_bf = decT + (size_t)D * H;             // [2048][256]

        prep_t<<<dim3(512), dim3(256), 0, stream>>>(enc_w, dec_w, encT, decT);

        // m_e = x @ enc_w : M=2048 N=256 K=1024, 32x32 tiles, BK=128 -> 512 blocks
        gemm1_bk128<<<dim3(H / 32, B / 32), dim3(256), 0, stream>>>(x, encT, m_e, me_bf);
        // m_d = m_e @ dec_w : K-resident, 32x64 tiles -> 1024 blocks
        gemm2_kres<<<dim3(D / 64, B / 32), dim3(256), 0, stream>>>(me_bf, decT, m_d);
    } else {
        gemm_f32<64, 32, 4, 2><<<dim3(H / 32, B / 64), dim3(256), 0, stream>>>(x, enc_w, m_e, B, H, D);
        gemm_f32<64, 64, 4, 4><<<dim3(D / 64, B / 64), dim3(256), 0, stream>>>(m_e, dec_w, m_d, B, D, H);
    }
}

// Round 7
// 25.337 us; speedup vs baseline: 1.3509x; 1.1518x over previous
//
#include <hip/hip_runtime.h>

// SNN autoencoder collapses to: m_e = x @ enc_w ; m_d = m_e @ dec_w
// (spike state is exactly {0,1}, so 0.9*s - 0.9*(s>0.9) == 0 every step;
//  membranes are recomputed from the constant input current each step).
// Output: d_out = [m_d (2048x1024) | m_e (2048x256)], fp32.
//
// 3 dispatches (r3 structure; single change vs r3: gemm1 BK 64->128, bf16 A):
//   prep   : x->bf16, enc->bf16 transposed, dec->bf16 transposed (1536 blocks)
//   gemm1  : m_e = x_bf @ encT — 32x32 tiles, BK=128 (8 barrier iters), dbuf
//   gemm2  : m_d = m_e @ decT (K=256 LDS-resident, 1 barrier, 1024 blocks)

typedef __attribute__((ext_vector_type(8))) short bf16x8;
typedef __attribute__((ext_vector_type(4))) float f32x4;
typedef __attribute__((ext_vector_type(8))) unsigned short ushort8;

__device__ __forceinline__ unsigned short f2bf(float f) {
    unsigned u = __builtin_bit_cast(unsigned, f);
    unsigned r = u + 0x7FFFu + ((u >> 16) & 1u);   // RNE
    return (unsigned short)(r >> 16);
}

__device__ __forceinline__ void gload_lds16(const void* src, void* dst) {
    __builtin_amdgcn_global_load_lds(
        (const __attribute__((address_space(1))) void*)src,
        (__attribute__((address_space(3))) void*)dst, 16, 0, 0);
}

// ---- stage ROWS x 64 bf16 tile (8 chunks/row, XOR-swizzled source, rule #21) ----
template <int ROWS>
__device__ __forceinline__ void stage_tile(const unsigned short* __restrict__ g,
                                           int ld, unsigned short* lds, int t) {
    #pragma unroll
    for (int c = 0; c < ROWS / 32; ++c) {
        const int idx = c * 256 + t;          // 16B-chunk index in tile
        const int row = idx >> 3;
        const int chunk = (idx & 7) ^ (row & 7);
        const unsigned short* src = g + (size_t)row * ld + chunk * 8;
        unsigned short* dst = lds + (size_t)(idx & ~63) * 8;  // wave-uniform base
        gload_lds16(src, dst);
    }
}

// ---------------- GEMM1: 32x32 tiles, BK=128, bf16 A (8 barrier iters) -------
// LDS: As[2][32*128] + Bs[2][32*128] bf16 = 32 KB. Grid 512 -> 2 blocks/CU.
__global__ __launch_bounds__(256) void gemm1_bk128b(
    const unsigned short* __restrict__ A,   // x_bf [2048][1024] bf16
    const unsigned short* __restrict__ Bt,  // encT [256][1024] bf16
    float* __restrict__ C,                  // m_e  [2048][256] f32
    unsigned short* __restrict__ Cbf)       // me_bf[2048][256] bf16
{
    constexpr int N = 256, K = 1024, BK = 128, NT = K / BK;  // NT = 8
    __shared__ __align__(16) unsigned short As[2][32 * BK];
    __shared__ __align__(16) unsigned short Bs[2][32 * BK];

    const int t = threadIdx.x;
    const int lane = t & 63;
    const int l15 = lane & 15, l4 = lane >> 4;
    const int wid = t >> 6;
    const int wr = wid >> 1, wc = wid & 1;          // 2x2 waves, WM=WN=16
    const int brow = blockIdx.y * 32, bcol = blockIdx.x * 32;

    const unsigned short* Ab = A + (size_t)brow * K;
    const unsigned short* Bb = Bt + (size_t)bcol * K;

    // tile [32 rows][128 k] bf16 = 512 x 16B chunks, 16 chunks/row, 2/thread
    auto stage = [&](int kt, int buf) {
        #pragma unroll
        for (int c = 0; c < 2; ++c) {
            const int idx = c * 256 + t;
            const int row = idx >> 4;
            const int ch = (idx & 15) ^ (row & 15);
            gload_lds16(Ab + (size_t)row * K + kt * BK + ch * 8,
                        &As[buf][(idx & ~63) * 8]);
        }
        #pragma unroll
        for (int c = 0; c < 2; ++c) {
            const int idx = c * 256 + t;
            const int row = idx >> 4;
            const int ch = (idx & 15) ^ (row & 15);
            gload_lds16(Bb + (size_t)row * K + kt * BK + ch * 8,
                        &Bs[buf][(idx & ~63) * 8]);
        }
    };

    f32x4 acc = {0.f, 0.f, 0.f, 0.f};
    stage(0, 0);
    for (int kt = 0; kt < NT; ++kt) {
        __syncthreads();            // stage(kt) landed; other buffer reads done
        if (kt + 1 < NT) stage(kt + 1, (kt + 1) & 1);
        const unsigned short* Asb = As[kt & 1];
        const unsigned short* Bsb = Bs[kt & 1];
        const int ra = wr * 16 + l15;
        const int rb = wc * 16 + l15;
        #pragma unroll
        for (int s = 0; s < 4; ++s) {           // 4 x 32-k MFMA steps
            const int ca = (s * 4 + l4) ^ (ra & 15);
            const bf16x8 aF = *(const bf16x8*)&Asb[ra * BK + ca * 8];
            const int cb = (s * 4 + l4) ^ (rb & 15);
            const bf16x8 bF = *(const bf16x8*)&Bsb[rb * BK + cb * 8];
            acc = __builtin_amdgcn_mfma_f32_16x16x32_bf16(aF, bF, acc, 0, 0, 0);
        }
    }

    #pragma unroll
    for (int reg = 0; reg < 4; ++reg) {
        const int row = brow + wr * 16 + l4 * 4 + reg;
        const int col = bcol + wc * 16 + l15;
        const float v = acc[reg];
        C[(size_t)row * N + col] = v;
        Cbf[(size_t)row * N + col] = f2bf(v);
    }
}

// ---------------- GEMM2: K=256 LDS-resident, single barrier (r3-proven) ------
__global__ __launch_bounds__(256) void gemm2_kres(
    const unsigned short* __restrict__ A,   // [2048][256] bf16 (me_bf)
    const unsigned short* __restrict__ B,   // [1024][256] bf16 (decT)
    float* __restrict__ C)                  // [2048][1024] f32 (m_d)
{
    constexpr int K = 256, N = 1024;
    __shared__ __align__(16) unsigned short As[4][32 * 64];  // 16 KB
    __shared__ __align__(16) unsigned short Bs[4][64 * 64];  // 32 KB

    const int t = threadIdx.x;
    const int lane = t & 63;
    const int l15 = lane & 15, l4 = lane >> 4;
    const int wid = t >> 6;
    const int wr = wid >> 1, wc = wid & 1;
    const int brow = blockIdx.y * 32, bcol = blockIdx.x * 64;

    #pragma unroll
    for (int kt = 0; kt < 4; ++kt) {
        stage_tile<32>(A + (size_t)brow * K + kt * 64, K, As[kt], t);
        stage_tile<64>(B + (size_t)bcol * K + kt * 64, K, Bs[kt], t);
    }
    __syncthreads();

    f32x4 acc[2] = {{0.f, 0.f, 0.f, 0.f}, {0.f, 0.f, 0.f, 0.f}};
    #pragma unroll
    for (int kt = 0; kt < 4; ++kt)
        #pragma unroll
        for (int s = 0; s < 2; ++s) {
            const int ra = wr * 16 + l15;
            const int cha = (s * 4 + l4) ^ (ra & 7);
            bf16x8 aF = *(const bf16x8*)&As[kt][ra * 64 + cha * 8];
            #pragma unroll
            for (int j = 0; j < 2; ++j) {
                const int rb = wc * 32 + j * 16 + l15;
                const int chb = (s * 4 + l4) ^ (rb & 7);
                bf16x8 bF = *(const bf16x8*)&Bs[kt][rb * 64 + chb * 8];
                acc[j] = __builtin_amdgcn_mfma_f32_16x16x32_bf16(aF, bF, acc[j], 0, 0, 0);
            }
        }

    #pragma unroll
    for (int j = 0; j < 2; ++j)
        #pragma unroll
        for (int reg = 0; reg < 4; ++reg) {
            const int row = brow + wr * 16 + l4 * 4 + reg;
            const int col = bcol + wc * 32 + j * 16 + l15;
            C[(size_t)row * N + col] = acc[j][reg];
        }
}

// ---------------- fused prep: x->bf16 | enc transpose | dec transpose --------
__global__ __launch_bounds__(256) void prep(
    const float* __restrict__ x, const float* __restrict__ enc,
    const float* __restrict__ dec, unsigned short* __restrict__ x_bf,
    unsigned short* __restrict__ encT, unsigned short* __restrict__ decT)
{
    __shared__ unsigned short tile[32][33];
    const int bid = blockIdx.x;
    const int t = threadIdx.x;

    if (bid < 1024) {               // ---- x cvt: 2M elems, 8/thread ----
        const int i = bid * 256 + t;
        float4 a = ((const float4*)x)[2 * i];
        float4 b = ((const float4*)x)[2 * i + 1];
        ushort8 v;
        v[0] = f2bf(a.x); v[1] = f2bf(a.y); v[2] = f2bf(a.z); v[3] = f2bf(a.w);
        v[4] = f2bf(b.x); v[5] = f2bf(b.y); v[6] = f2bf(b.z); v[7] = f2bf(b.w);
        ((ushort8*)x_bf)[i] = v;
        return;
    }
    const float* in; unsigned short* out; int R, C, bx, by;
    if (bid < 1280) {               // enc [1024][256] -> encT [256][1024]
        const int bb = bid - 1024;
        in = enc; out = encT; R = 1024; C = 256; bx = bb % 8; by = bb / 8;
    } else {                        // dec [256][1024] -> decT [1024][256]
        const int bb = bid - 1280;
        in = dec; out = decT; R = 256; C = 1024; bx = bb % 32; by = bb / 32;
    }
    const int r0 = by * 32, c0 = bx * 32;
    const int tx = t % 32, ty = t / 32;       // 32 x 8
    #pragma unroll
    for (int k = 0; k < 4; ++k) {
        const int lr = ty + k * 8;
        tile[lr][tx] = f2bf(in[(size_t)(r0 + lr) * C + c0 + tx]);
    }
    __syncthreads();
    #pragma unroll
    for (int k = 0; k < 4; ++k) {
        const int lc = ty + k * 8;
        out[(size_t)(c0 + lc) * R + r0 + tx] = tile[tx][lc];
    }
}

// ---------------- fp32 fallback ----------------
#define BKF 32
#define PADF 4
template <int BM, int BN, int TM, int TN>
__global__ __launch_bounds__(256) void gemm_f32(
    const float* __restrict__ A, const float* __restrict__ B,
    float* __restrict__ C, int M, int N, int K)
{
    __shared__ float As[BKF][BM + PADF];
    __shared__ float Bs[BKF][BN + PADF];
    const int t = threadIdx.x;
    const int brow = blockIdx.y * BM, bcol = blockIdx.x * BN;
    constexpr int NTX = BN / TN;
    const int tx = t % NTX, ty = t / NTX;
    float acc[TM][TN];
    #pragma unroll
    for (int i = 0; i < TM; ++i)
        #pragma unroll
        for (int j = 0; j < TN; ++j) acc[i][j] = 0.f;
    for (int k0 = 0; k0 < K; k0 += BKF) {
        #pragma unroll
        for (int v = t; v < BM * BKF / 4; v += 256) {
            const int row = v / (BKF / 4), kv = v % (BKF / 4);
            const float4 val = *(const float4*)&A[(size_t)(brow + row) * K + k0 + kv * 4];
            As[kv * 4 + 0][row] = val.x; As[kv * 4 + 1][row] = val.y;
            As[kv * 4 + 2][row] = val.z; As[kv * 4 + 3][row] = val.w;
        }
        #pragma unroll
        for (int v = t; v < BKF * BN / 4; v += 256) {
            const int kk = v / (BN / 4), cv = v % (BN / 4);
            *(float4*)&Bs[kk][cv * 4] = *(const float4*)&B[(size_t)(k0 + kk) * N + bcol + cv * 4];
        }
        __syncthreads();
        #pragma unroll
        for (int k = 0; k < BKF; ++k) {
            float a[TM], b[TN];
            #pragma unroll
            for (int i = 0; i < TM; ++i) a[i] = As[k][ty * TM + i];
            #pragma unroll
            for (int j = 0; j < TN; ++j) b[j] = Bs[k][tx * TN + j];
            #pragma unroll
            for (int i = 0; i < TM; ++i)
                #pragma unroll
                for (int j = 0; j < TN; ++j) acc[i][j] = fmaf(a[i], b[j], acc[i][j]);
        }
        __syncthreads();
    }
    #pragma unroll
    for (int i = 0; i < TM; ++i)
        #pragma unroll
        for (int j = 0; j < TN; ++j)
            C[(size_t)(brow + ty * TM + i) * N + bcol + tx * TN + j] = acc[i][j];
}

extern "C" void kernel_launch(void* const* d_in, const int* in_sizes, int n_in,
                              void* d_out, int out_size, void* d_ws, size_t ws_size,
                              hipStream_t stream) {
    const float* x     = (const float*)d_in[0];  // [2048, 1024]
    const float* enc_w = (const float*)d_in[1];  // [1024, 256]
    const float* dec_w = (const float*)d_in[2];  // [256, 1024]

    const int B = 2048, D = 1024, H = 256;
    float* m_d = (float*)d_out;
    float* m_e = (float*)d_out + (size_t)B * D;

    const size_t need = (size_t)B * D * 2 + (size_t)D * H * 2 * 2 + (size_t)B * H * 2;
    if (ws_size >= need) {
        unsigned short* x_bf  = (unsigned short*)d_ws;            // [2048][1024]
        unsigned short* encT  = x_bf + (size_t)B * D;             // [256][1024]
        unsigned short* decT  = encT + (size_t)H * D;             // [1024][256]
        unsigned short* me_bf = decT + (size_t)D * H;             // [2048][256]

        prep<<<dim3(1536), dim3(256), 0, stream>>>(x, enc_w, dec_w, x_bf, encT, decT);

        // m_e = x @ enc_w : M=2048 N=256 K=1024, 32x32 tiles, BK=128 -> 512 blocks
        gemm1_bk128b<<<dim3(H / 32, B / 32), dim3(256), 0, stream>>>(x_bf, encT, m_e, me_bf);
        // m_d = m_e @ dec_w : K-resident, 32x64 tiles -> 1024 blocks
        gemm2_kres<<<dim3(D / 64, B / 32), dim3(256), 0, stream>>>(me_bf, decT, m_d);
    } else {
        gemm_f32<64, 32, 4, 2><<<dim3(H / 32, B / 64), dim3(256), 0, stream>>>(x, enc_w, m_e, B, H, D);
        gemm_f32<64, 64, 4, 4><<<dim3(D / 64, B / 64), dim3(256), 0, stream>>>(m_e, dec_w, m_d, B, D, H);
    }
}

// Round 8
// 23.739 us; speedup vs baseline: 1.4418x; 1.0673x over previous
//
#include <hip/hip_runtime.h>

// SNN autoencoder collapses to: m_e = x @ enc_w ; m_d = m_e @ dec_w
// (spike state is exactly {0,1}, so 0.9*s - 0.9*(s>0.9) == 0 every step;
//  membranes are recomputed from the constant input current each step).
// Output: d_out = [m_d (2048x1024) | m_e (2048x256)], fp32.
//
// 3 dispatches (r7 structure; param changes only):
//   prep   : x->bf16, enc->bf16 transposed, dec->bf16 transposed (1536 blocks)
//   gemm1  : m_e = x_bf @ encT — 32x32 tiles, BK=256 (4 barrier iters), dbuf,
//            LDS 64 KB, grid 512 -> 2 blocks/CU
//   gemm2  : m_d = m_e @ decT — K=256 LDS-resident, BN=128, LDS 80 KB,
//            grid 512 -> 2 blocks/CU, ONE fully-resident round, 1 barrier

typedef __attribute__((ext_vector_type(8))) short bf16x8;
typedef __attribute__((ext_vector_type(4))) float f32x4;
typedef __attribute__((ext_vector_type(8))) unsigned short ushort8;

__device__ __forceinline__ unsigned short f2bf(float f) {
    unsigned u = __builtin_bit_cast(unsigned, f);
    unsigned r = u + 0x7FFFu + ((u >> 16) & 1u);   // RNE
    return (unsigned short)(r >> 16);
}

__device__ __forceinline__ void gload_lds16(const void* src, void* dst) {
    __builtin_amdgcn_global_load_lds(
        (const __attribute__((address_space(1))) void*)src,
        (__attribute__((address_space(3))) void*)dst, 16, 0, 0);
}

// ---- stage ROWS x 64 bf16 tile (8 chunks/row, XOR-swizzled source, rule #21) ----
template <int ROWS>
__device__ __forceinline__ void stage_tile(const unsigned short* __restrict__ g,
                                           int ld, unsigned short* lds, int t) {
    #pragma unroll
    for (int c = 0; c < ROWS / 32; ++c) {
        const int idx = c * 256 + t;          // 16B-chunk index in tile
        const int row = idx >> 3;
        const int chunk = (idx & 7) ^ (row & 7);
        const unsigned short* src = g + (size_t)row * ld + chunk * 8;
        unsigned short* dst = lds + (size_t)(idx & ~63) * 8;  // wave-uniform base
        gload_lds16(src, dst);
    }
}

// ---------------- GEMM1: 32x32 tiles, BK=256 (4 barrier iters), dbuf ---------
// LDS: As[2][32*256] + Bs[2][32*256] bf16 = 64 KB. Grid 512 -> 2 blocks/CU.
__global__ __launch_bounds__(256) void gemm1_bk256(
    const unsigned short* __restrict__ A,   // x_bf [2048][1024] bf16
    const unsigned short* __restrict__ Bt,  // encT [256][1024] bf16
    float* __restrict__ C,                  // m_e  [2048][256] f32
    unsigned short* __restrict__ Cbf)       // me_bf[2048][256] bf16
{
    constexpr int N = 256, K = 1024, BK = 256, NT = K / BK;  // NT = 4
    __shared__ __align__(16) unsigned short As[2][32 * BK];
    __shared__ __align__(16) unsigned short Bs[2][32 * BK];

    const int t = threadIdx.x;
    const int lane = t & 63;
    const int l15 = lane & 15, l4 = lane >> 4;
    const int wid = t >> 6;
    const int wr = wid >> 1, wc = wid & 1;          // 2x2 waves, WM=WN=16
    const int brow = blockIdx.y * 32, bcol = blockIdx.x * 32;

    const unsigned short* Ab = A + (size_t)brow * K;
    const unsigned short* Bb = Bt + (size_t)bcol * K;

    // tile [32 rows][256 k] bf16 = 1024 x 16B chunks, 32 chunks/row, 4/thread
    auto stage = [&](int kt, int buf) {
        #pragma unroll
        for (int c = 0; c < 4; ++c) {
            const int idx = c * 256 + t;
            const int row = idx >> 5;
            const int ch = (idx & 31) ^ (row & 31);
            gload_lds16(Ab + (size_t)row * K + kt * BK + ch * 8,
                        &As[buf][(idx & ~63) * 8]);
        }
        #pragma unroll
        for (int c = 0; c < 4; ++c) {
            const int idx = c * 256 + t;
            const int row = idx >> 5;
            const int ch = (idx & 31) ^ (row & 31);
            gload_lds16(Bb + (size_t)row * K + kt * BK + ch * 8,
                        &Bs[buf][(idx & ~63) * 8]);
        }
    };

    f32x4 acc = {0.f, 0.f, 0.f, 0.f};
    stage(0, 0);
    for (int kt = 0; kt < NT; ++kt) {
        __syncthreads();            // stage(kt) landed; other buffer reads done
        if (kt + 1 < NT) stage(kt + 1, (kt + 1) & 1);
        const unsigned short* Asb = As[kt & 1];
        const unsigned short* Bsb = Bs[kt & 1];
        const int ra = wr * 16 + l15;
        const int rb = wc * 16 + l15;
        #pragma unroll
        for (int s = 0; s < 8; ++s) {           // 8 x 32-k MFMA steps
            const int ca = (s * 4 + l4) ^ (ra & 31);
            const bf16x8 aF = *(const bf16x8*)&Asb[ra * BK + ca * 8];
            const int cb = (s * 4 + l4) ^ (rb & 31);
            const bf16x8 bF = *(const bf16x8*)&Bsb[rb * BK + cb * 8];
            acc = __builtin_amdgcn_mfma_f32_16x16x32_bf16(aF, bF, acc, 0, 0, 0);
        }
    }

    #pragma unroll
    for (int reg = 0; reg < 4; ++reg) {
        const int row = brow + wr * 16 + l4 * 4 + reg;
        const int col = bcol + wc * 16 + l15;
        const float v = acc[reg];
        C[(size_t)row * N + col] = v;
        Cbf[(size_t)row * N + col] = f2bf(v);
    }
}

// ---------------- GEMM2: K=256 LDS-resident, BN=128, one resident round ------
// LDS: As 16 KB + Bs 64 KB = 80 KB. Grid 512 -> 2 blocks/CU, all resident.
__global__ __launch_bounds__(256) void gemm2_kres128(
    const unsigned short* __restrict__ A,   // [2048][256] bf16 (me_bf)
    const unsigned short* __restrict__ B,   // [1024][256] bf16 (decT)
    float* __restrict__ C)                  // [2048][1024] f32 (m_d)
{
    constexpr int K = 256, N = 1024;
    __shared__ __align__(16) unsigned short As[4][32 * 64];   // 16 KB
    __shared__ __align__(16) unsigned short Bs[4][128 * 64];  // 64 KB

    const int t = threadIdx.x;
    const int lane = t & 63;
    const int l15 = lane & 15, l4 = lane >> 4;
    const int wid = t >> 6;
    const int wr = wid >> 1, wc = wid & 1;          // 2x2 waves: WM=16, WN=64
    const int brow = blockIdx.y * 32, bcol = blockIdx.x * 128;

    #pragma unroll
    for (int kt = 0; kt < 4; ++kt) {
        stage_tile<32>(A + (size_t)brow * K + kt * 64, K, As[kt], t);
        stage_tile<128>(B + (size_t)bcol * K + kt * 64, K, Bs[kt], t);
    }
    __syncthreads();

    f32x4 acc[4];
    #pragma unroll
    for (int j = 0; j < 4; ++j) acc[j] = {0.f, 0.f, 0.f, 0.f};

    #pragma unroll
    for (int kt = 0; kt < 4; ++kt)
        #pragma unroll
        for (int s = 0; s < 2; ++s) {
            const int ra = wr * 16 + l15;
            const int cha = (s * 4 + l4) ^ (ra & 7);
            const bf16x8 aF = *(const bf16x8*)&As[kt][ra * 64 + cha * 8];
            #pragma unroll
            for (int j = 0; j < 4; ++j) {
                const int rb = wc * 64 + j * 16 + l15;
                const int chb = (s * 4 + l4) ^ (rb & 7);
                const bf16x8 bF = *(const bf16x8*)&Bs[kt][rb * 64 + chb * 8];
                acc[j] = __builtin_amdgcn_mfma_f32_16x16x32_bf16(aF, bF, acc[j], 0, 0, 0);
            }
        }

    #pragma unroll
    for (int j = 0; j < 4; ++j)
        #pragma unroll
        for (int reg = 0; reg < 4; ++reg) {
            const int row = brow + wr * 16 + l4 * 4 + reg;
            const int col = bcol + wc * 64 + j * 16 + l15;
            C[(size_t)row * N + col] = acc[j][reg];
        }
}

// ---------------- fused prep: x->bf16 | enc transpose | dec transpose --------
__global__ __launch_bounds__(256) void prep(
    const float* __restrict__ x, const float* __restrict__ enc,
    const float* __restrict__ dec, unsigned short* __restrict__ x_bf,
    unsigned short* __restrict__ encT, unsigned short* __restrict__ decT)
{
    __shared__ unsigned short tile[32][33];
    const int bid = blockIdx.x;
    const int t = threadIdx.x;

    if (bid < 1024) {               // ---- x cvt: 2M elems, 8/thread ----
        const int i = bid * 256 + t;
        float4 a = ((const float4*)x)[2 * i];
        float4 b = ((const float4*)x)[2 * i + 1];
        ushort8 v;
        v[0] = f2bf(a.x); v[1] = f2bf(a.y); v[2] = f2bf(a.z); v[3] = f2bf(a.w);
        v[4] = f2bf(b.x); v[5] = f2bf(b.y); v[6] = f2bf(b.z); v[7] = f2bf(b.w);
        ((ushort8*)x_bf)[i] = v;
        return;
    }
    const float* in; unsigned short* out; int R, C, bx, by;
    if (bid < 1280) {               // enc [1024][256] -> encT [256][1024]
        const int bb = bid - 1024;
        in = enc; out = encT; R = 1024; C = 256; bx = bb % 8; by = bb / 8;
    } else {                        // dec [256][1024] -> decT [1024][256]
        const int bb = bid - 1280;
        in = dec; out = decT; R = 256; C = 1024; bx = bb % 32; by = bb / 32;
    }
    const int r0 = by * 32, c0 = bx * 32;
    const int tx = t % 32, ty = t / 32;       // 32 x 8
    #pragma unroll
    for (int k = 0; k < 4; ++k) {
        const int lr = ty + k * 8;
        tile[lr][tx] = f2bf(in[(size_t)(r0 + lr) * C + c0 + tx]);
    }
    __syncthreads();
    #pragma unroll
    for (int k = 0; k < 4; ++k) {
        const int lc = ty + k * 8;
        out[(size_t)(c0 + lc) * R + r0 + tx] = tile[tx][lc];
    }
}

// ---------------- fp32 fallback ----------------
#define BKF 32
#define PADF 4
template <int BM, int BN, int TM, int TN>
__global__ __launch_bounds__(256) void gemm_f32(
    const float* __restrict__ A, const float* __restrict__ B,
    float* __restrict__ C, int M, int N, int K)
{
    __shared__ float As[BKF][BM + PADF];
    __shared__ float Bs[BKF][BN + PADF];
    const int t = threadIdx.x;
    const int brow = blockIdx.y * BM, bcol = blockIdx.x * BN;
    constexpr int NTX = BN / TN;
    const int tx = t % NTX, ty = t / NTX;
    float acc[TM][TN];
    #pragma unroll
    for (int i = 0; i < TM; ++i)
        #pragma unroll
        for (int j = 0; j < TN; ++j) acc[i][j] = 0.f;
    for (int k0 = 0; k0 < K; k0 += BKF) {
        #pragma unroll
        for (int v = t; v < BM * BKF / 4; v += 256) {
            const int row = v / (BKF / 4), kv = v % (BKF / 4);
            const float4 val = *(const float4*)&A[(size_t)(brow + row) * K + k0 + kv * 4];
            As[kv * 4 + 0][row] = val.x; As[kv * 4 + 1][row] = val.y;
            As[kv * 4 + 2][row] = val.z; As[kv * 4 + 3][row] = val.w;
        }
        #pragma unroll
        for (int v = t; v < BKF * BN / 4; v += 256) {
            const int kk = v / (BN / 4), cv = v % (BN / 4);
            *(float4*)&Bs[kk][cv * 4] = *(const float4*)&B[(size_t)(k0 + kk) * N + bcol + cv * 4];
        }
        __syncthreads();
        #pragma unroll
        for (int k = 0; k < BKF; ++k) {
            float a[TM], b[TN];
            #pragma unroll
            for (int i = 0; i < TM; ++i) a[i] = As[k][ty * TM + i];
            #pragma unroll
            for (int j = 0; j < TN; ++j) b[j] = Bs[k][tx * TN + j];
            #pragma unroll
            for (int i = 0; i < TM; ++i)
                #pragma unroll
                for (int j = 0; j < TN; ++j) acc[i][j] = fmaf(a[i], b[j], acc[i][j]);
        }
        __syncthreads();
    }
    #pragma unroll
    for (int i = 0; i < TM; ++i)
        #pragma unroll
        for (int j = 0; j < TN; ++j)
            C[(size_t)(brow + ty * TM + i) * N + bcol + tx * TN + j] = acc[i][j];
}

extern "C" void kernel_launch(void* const* d_in, const int* in_sizes, int n_in,
                              void* d_out, int out_size, void* d_ws, size_t ws_size,
                              hipStream_t stream) {
    const float* x     = (const float*)d_in[0];  // [2048, 1024]
    const float* enc_w = (const float*)d_in[1];  // [1024, 256]
    const float* dec_w = (const float*)d_in[2];  // [256, 1024]

    const int B = 2048, D = 1024, H = 256;
    float* m_d = (float*)d_out;
    float* m_e = (float*)d_out + (size_t)B * D;

    const size_t need = (size_t)B * D * 2 + (size_t)D * H * 2 * 2 + (size_t)B * H * 2;
    if (ws_size >= need) {
        unsigned short* x_bf  = (unsigned short*)d_ws;            // [2048][1024]
        unsigned short* encT  = x_bf + (size_t)B * D;             // [256][1024]
        unsigned short* decT  = encT + (size_t)H * D;             // [1024][256]
        unsigned short* me_bf = decT + (size_t)D * H;             // [2048][256]

        prep<<<dim3(1536), dim3(256), 0, stream>>>(x, enc_w, dec_w, x_bf, encT, decT);

        // m_e = x @ enc_w : M=2048 N=256 K=1024, 32x32 tiles, BK=256 -> 512 blocks
        gemm1_bk256<<<dim3(H / 32, B / 32), dim3(256), 0, stream>>>(x_bf, encT, m_e, me_bf);
        // m_d = m_e @ dec_w : K-resident, 32x128 tiles -> 512 blocks
        gemm2_kres128<<<dim3(D / 128, B / 32), dim3(256), 0, stream>>>(me_bf, decT, m_d);
    } else {
        gemm_f32<64, 32, 4, 2><<<dim3(H / 32, B / 64), dim3(256), 0, stream>>>(x, enc_w, m_e, B, H, D);
        gemm_f32<64, 64, 4, 4><<<dim3(D / 64, B / 64), dim3(256), 0, stream>>>(m_e, dec_w, m_d, B, D, H);
    }
}